// Round 1
// 214.413 us; speedup vs baseline: 1.0347x; 1.0347x over previous
//
#include <hip/hip_runtime.h>
#include <hip/hip_bf16.h>
#include <cstdint>

#define B_ 16
#define S_ 2048
#define H_ 1024
#define D_ 64
#define R_ 2048
#define M_ (B_*S_)   // 32768 rows
#define N_ 128       // 2*D
#define NC_ 16       // K chunks of 64

typedef short short8 __attribute__((ext_vector_type(8)));
typedef float f32x4  __attribute__((ext_vector_type(4)));

__device__ __forceinline__ unsigned short f2bf(float f) {
    unsigned u = __builtin_bit_cast(unsigned, f);
    u += 0x7FFFu + ((u >> 16) & 1u);     // RNE
    return (unsigned short)(u >> 16);
}
__device__ __forceinline__ unsigned pk2(float a, float b) {
    return (unsigned)f2bf(a) | ((unsigned)f2bf(b) << 16);
}
__device__ __forceinline__ float bflo(unsigned u) {
    return __builtin_bit_cast(float, u << 16);
}
__device__ __forceinline__ float bfhi(unsigned u) {
    return __builtin_bit_cast(float, u & 0xFFFF0000u);
}

typedef const __attribute__((address_space(1))) void gvoid_t;
typedef __attribute__((address_space(3))) void lvoid_t;
__device__ __forceinline__ void gload16(const void* g, void* l) {
    __builtin_amdgcn_global_load_lds((gvoid_t*)g, (lvoid_t*)l, 16, 0, 0);
}

// ---------------------------------------------------------------------------
// Kernel 0: Wt[n][k] = bf16(W[k][n]);  [128][1024] ushort.
// v2: coalesced. Block = 16 k-rows x 128 n; read rows coalesced into LDS,
// write transposed as short8 (16B) per thread. Grid 64 x 256.
// ---------------------------------------------------------------------------
__global__ void build_wt(const float* __restrict__ W, unsigned short* __restrict__ Wt) {
    __shared__ float tile[16][128];      // 8 KiB; bank = n%32 (128 ≡ 0 mod 32)
    const int tid = threadIdx.x;
    const int k0  = blockIdx.x * 16;
    #pragma unroll
    for (int i = 0; i < 8; i++) {
        const int k = i * 2 + (tid >> 7);                 // two rows per iter
        tile[k][tid & 127] = W[(size_t)(k0 + k) * N_ + (tid & 127)];
    }
    __syncthreads();
    const int n  = tid >> 1;
    const int kh = (tid & 1) * 8;
    short8 v;
    #pragma unroll
    for (int e = 0; e < 8; e++) v[e] = (short)f2bf(tile[kh + e][n]);  // 2-way LDS (free)
    *(short8*)(Wt + (size_t)n * 1024 + k0 + kh) = v;      // 16B aligned store
}

// ---------------------------------------------------------------------------
// Kernel 1: qk[m][0:128] = bf16( RoPE( A[m][:] @ W + b ) ), packed 2/uint.
// Block 256 = 4 waves; wave owns 16 rows x 128 cols (8 MFMA 16x16x32 tiles).
// A (fp32) and Wt (bf16) double-buffer-staged via global_load_lds (async DMA),
// XOR-swizzled on the GLOBAL side so LDS dest stays lane-contiguous.
// One barrier per K-chunk; prefetch issued right after it (m97 structure).
// DMA core untouched vs v1 (HBM-saturated per Little's-law check);
// epilogue v2: fract/sin/cos hoisted (4 distinct per row, not 8).
// ---------------------------------------------------------------------------
__launch_bounds__(256, 2)
__global__ void gemm_rope(const float* __restrict__ A,            // [M][1024]
                          const unsigned short* __restrict__ Wt,  // [128][1024] bf16
                          const float* __restrict__ bias,         // [128]
                          const int* __restrict__ pos_ids,        // [M]
                          unsigned* __restrict__ qk)              // [M][64] bf16x2
{
    __shared__ __align__(16) float          abuf[2][64 * 64];      // 2 x 16 KiB
    __shared__ __align__(16) unsigned short wbuf[2][N_ * 64];      // 2 x 16 KiB

    const int tid  = threadIdx.x;
    const int wave = tid >> 6, lane = tid & 63;
    const int ln15 = lane & 15, quad = lane >> 4, key = ln15 & 7;
    const int m0   = blockIdx.x * 64;

    // ---- staging address precompute (per lane)
    const float* a_g[4];
    const unsigned short* w_g[4];
    int a_lo[4], w_lo[4];
    #pragma unroll
    for (int t = 0; t < 4; t++) {
        const int rl = wave * 16 + t * 4 + (lane >> 4);            // A row in block
        a_g[t]  = A + (size_t)(m0 + rl) * H_ + (((lane & 15) ^ (rl & 7)) << 2);
        a_lo[t] = (wave * 16 + t * 4) * 64;                        // uniform LDS base (floats)
        const int n = (wave * 4 + t) * 8 + (lane >> 3);            // Wt row
        w_g[t]  = Wt + (size_t)n * 1024 + (((lane & 7) ^ (n & 7)) << 3);
        w_lo[t] = (wave * 4 + t) * 8 * 64;                         // uniform LDS base (shorts)
    }

    f32x4 acc[8];
    #pragma unroll
    for (int j = 0; j < 8; j++) acc[j] = (f32x4)0.f;

    // ---- prologue: stage chunk 0 into buf 0
    #pragma unroll
    for (int t = 0; t < 4; t++) {
        gload16(a_g[t], &abuf[0][a_lo[t]]);
        gload16(w_g[t], &wbuf[0][w_lo[t]]);
    }

    const float* ab_lane_base;  // set per buffer below
    for (int kc = 0; kc < NC_; kc++) {
        __syncthreads();                      // drains stage(kc) DMA; all waves ready
        if (kc + 1 < NC_) {                   // async prefetch overlaps full compute phase
            const int nb = (kc + 1) & 1;
            #pragma unroll
            for (int t = 0; t < 4; t++) {
                gload16(a_g[t] + (kc + 1) * 64, &abuf[nb][a_lo[t]]);
                gload16(w_g[t] + (kc + 1) * 64, &wbuf[nb][w_lo[t]]);
            }
        }
        const int cb = kc & 1;
        ab_lane_base = &abuf[cb][(wave * 16 + ln15) * 64];
        #pragma unroll
        for (int ks = 0; ks < 2; ks++) {
            const int g0 = ks * 8 + quad * 2;
            f32x4 r0 = *(const f32x4*)(ab_lane_base + ((g0 ^ key) << 2));
            f32x4 r1 = *(const f32x4*)(ab_lane_base + (((g0 + 1) ^ key) << 2));
            int4 ai;
            ai.x = (int)pk2(r0[0], r0[1]);
            ai.y = (int)pk2(r0[2], r0[3]);
            ai.z = (int)pk2(r1[0], r1[1]);
            ai.w = (int)pk2(r1[2], r1[3]);
            const short8 af = __builtin_bit_cast(short8, ai);
            const int p = ((ks * 4 + quad) ^ key) << 3;
            #pragma unroll
            for (int j = 0; j < 8; j++) {
                const short8 bf = *(const short8*)(&wbuf[cb][(j * 16 + ln15) * 64 + p]);
                acc[j] = __builtin_amdgcn_mfma_f32_16x16x32_bf16(af, bf, acc[j], 0, 0, 0);
            }
        }
    }

    // ---- epilogue: bias + RoPE (v_sin/v_cos in revolutions) + packed bf16 store
    // C/D layout: col = ln15 (within tile j), row = quad*4 + reg
    const int rbase = m0 + wave * 16 + quad * 4;
    float bv[8], invr[4];
    #pragma unroll
    for (int j = 0; j < 8; j++) bv[j] = bias[j * 16 + ln15];
    #pragma unroll
    for (int jj = 0; jj < 4; jj++) {
        const float fi = (float)((jj * 16 + ln15) >> 1);
        // inv_freq/(2pi) = exp2(-fi*log2(10000)/32) * 0.15915494
        invr[jj] = exp2f(fi * -0.41524101186092029f) * 0.15915494309189535f;
    }
    const bool odd = (ln15 & 1);
    #pragma unroll
    for (int reg = 0; reg < 4; reg++) {
        const int r = rbase + reg;
        const float pos = (float)pos_ids[r];
        float s_[4], c_[4];
        #pragma unroll
        for (int jj = 0; jj < 4; jj++) {      // j and j+4 share a frequency: 4 distinct
            const float fr = __builtin_amdgcn_fractf(pos * invr[jj]);
            s_[jj] = __builtin_amdgcn_sinf(fr);
            c_[jj] = __builtin_amdgcn_cosf(fr);
        }
        #pragma unroll
        for (int j = 0; j < 8; j++) {
            const int c = j * 16 + ln15;
            float v = acc[j][reg] + bv[j];
            float p = __shfl_xor(v, 1, 64);                 // partner column c^1
            float outv = odd ? fmaf(v, c_[j & 3], p * s_[j & 3])
                             : fmaf(v, c_[j & 3], -p * s_[j & 3]);
            float po = __shfl_xor(outv, 1, 64);
            if (!odd)
                qk[(size_t)r * 64 + (c >> 1)] = pk2(outv, po);
        }
    }
}

// ---------------------------------------------------------------------------
// Kernel 2: 16 lanes per relation (4 relations/wave); qk is packed bf16 pairs.
// lanes sub 0..7:  uint4 of qw[i0] . kw[i2];  sub 8..15: qw[i1] . kw[i3]
// 16B loads -> half the memory instructions, 4x fewer waves than v1.
// ---------------------------------------------------------------------------
__global__ void gather_dot(const unsigned* __restrict__ qk, const int* __restrict__ rel,
                           const float* __restrict__ mask, float* __restrict__ out)
{
    const int t    = blockIdx.x * 256 + threadIdx.x;
    const int w    = t >> 4;                       // relation 0..32767
    const int sub  = threadIdx.x & 15;
    const int b    = w >> 11;                      // 2048 relations per batch
    const int4 id4 = ((const int4*)rel)[w];
    const unsigned* base = qk + (size_t)b * S_ * 64;
    const int rq = (sub < 8) ? id4.x : id4.y;
    const int rk = (sub < 8) ? id4.z : id4.w;
    const int c4 = (sub & 7) * 4;
    const uint4 uq = *(const uint4*)(base + (size_t)rq * 64 + c4);        // q half
    const uint4 uk = *(const uint4*)(base + (size_t)rk * 64 + 32 + c4);   // k half
    float v;
    v  = bflo(uq.x) * bflo(uk.x) + bfhi(uq.x) * bfhi(uk.x);
    v += bflo(uq.y) * bflo(uk.y) + bfhi(uq.y) * bfhi(uk.y);
    v += bflo(uq.z) * bflo(uk.z) + bfhi(uq.z) * bfhi(uk.z);
    v += bflo(uq.w) * bflo(uk.w) + bfhi(uq.w) * bfhi(uk.w);
    #pragma unroll
    for (int off = 8; off; off >>= 1) v += __shfl_xor(v, off, 64);  // 16-lane butterfly
    if (sub == 0)
        out[w] = (v + (1.0f - mask[w]) * -1e12f) * 0.125f;
}

// ---------------------------------------------------------------------------
extern "C" void kernel_launch(void* const* d_in, const int* in_sizes, int n_in,
                              void* d_out, int out_size, void* d_ws, size_t ws_size,
                              hipStream_t stream) {
    const float* lhs  = (const float*)d_in[0];   // (B,S,H) fp32
    const float* W    = (const float*)d_in[1];   // (H,128) fp32
    const float* bias = (const float*)d_in[2];   // (128,)  fp32
    const int*   pos  = (const int*)d_in[3];     // (B,S)   int32
    const int*   rel  = (const int*)d_in[4];     // (B,R,4) int32
    const float* mask = (const float*)d_in[5];   // (B,R)   fp32
    float* out = (float*)d_out;                  // (B,R)   fp32

    unsigned short* Wt = (unsigned short*)d_ws;                      // 256 KiB
    unsigned* qk = (unsigned*)((char*)d_ws + (size_t)N_ * H_ * 2);   // 8 MiB bf16 pairs

    build_wt<<<64, 256, 0, stream>>>(W, Wt);
    gemm_rope<<<512, 256, 0, stream>>>(lhs, Wt, bias, pos, qk);
    gather_dot<<<2048, 256, 0, stream>>>(qk, rel, mask, out);
}